// Round 1
// baseline (293.773 us; speedup 1.0000x reference)
//
#include <hip/hip_runtime.h>
#include <math.h>

#define IN_C 512
#define HID  64
#define OUTC 40

// ---------------- histogram of dst ----------------
__global__ void k_hist(const int* __restrict__ dst, int E, int* __restrict__ cnt) {
    int i = blockIdx.x * blockDim.x + threadIdx.x;
    if (i < E) atomicAdd(&cnt[dst[i]], 1);
}

// ---------------- prefix scan (3 kernels) ----------------
__global__ void k_scan1(const int* __restrict__ cnt, int N,
                        int* __restrict__ rowptr, int* __restrict__ bsum) {
    __shared__ int s[256];
    int t = threadIdx.x;
    int i = blockIdx.x * 256 + t;
    int v = (i < N) ? cnt[i] : 0;
    int x = v;
    s[t] = x; __syncthreads();
    #pragma unroll
    for (int o = 1; o < 256; o <<= 1) {
        int y = (t >= o) ? s[t - o] : 0;
        __syncthreads();
        x += y; s[t] = x;
        __syncthreads();
    }
    if (i < N) rowptr[i] = x - v;          // exclusive
    if (t == 255) bsum[blockIdx.x] = x;    // block total
}

__global__ void k_scan2(const int* __restrict__ bsum, int nb, int* __restrict__ bpre) {
    __shared__ int s[256];
    int t = threadIdx.x;
    int v = (t < nb) ? bsum[t] : 0;
    int x = v;
    s[t] = x; __syncthreads();
    #pragma unroll
    for (int o = 1; o < 256; o <<= 1) {
        int y = (t >= o) ? s[t - o] : 0;
        __syncthreads();
        x += y; s[t] = x;
        __syncthreads();
    }
    bpre[t] = x - v;
}

__global__ void k_scan3(int* __restrict__ rowptr, const int* __restrict__ bpre,
                        const int* __restrict__ cnt, float* __restrict__ dinv,
                        int N, int E) {
    int i = blockIdx.x * blockDim.x + threadIdx.x;
    if (i < N) {
        rowptr[i] += bpre[i >> 8];
        dinv[i] = rsqrtf(1.0f + (float)cnt[i]);   // self-loop => deg >= 1
        if (i == 0) rowptr[N] = E;
    }
}

// ---------------- counting-sort fill ----------------
__global__ void k_fill(const int* __restrict__ src, const int* __restrict__ dst, int E,
                       const int* __restrict__ rowptr, int* __restrict__ fillc,
                       int* __restrict__ ssort) {
    int i = blockIdx.x * blockDim.x + threadIdx.x;
    if (i < E) {
        int d = dst[i];
        int p = rowptr[d] + atomicAdd(&fillc[d], 1);
        ssort[p] = src[i];
    }
}

// ---------------- GEMM1: h1s[i][c] = dinv[i] * dot(x[i,:512], W1[:,c]), c<64 ----------------
__global__ __launch_bounds__(256) void k_gemm1(const float* __restrict__ x,
                                               const float* __restrict__ W,
                                               const float* __restrict__ dinv,
                                               float* __restrict__ h1s, int N) {
    __shared__ float xsT[32 * 68];   // [k][r], stride 68 (16B-aligned rows, bank-spread)
    __shared__ float ws[32 * 64];    // [k][c]
    int t = threadIdx.x;
    int row0 = blockIdx.x * 64;
    int tx = t & 15, ty = t >> 4;

    float acc[4][4] = {};

    for (int kt = 0; kt < IN_C; kt += 32) {
        // stage x tile (64 rows x 32 k), transposed into xsT
        #pragma unroll
        for (int q0 = 0; q0 < 2; ++q0) {
            int q = t + q0 * 256;          // float4 index over 512
            int r = q >> 3, kq = q & 7;
            int row = row0 + r; if (row >= N) row = N - 1;
            const float4 v = *(const float4*)&x[(size_t)row * IN_C + kt + kq * 4];
            xsT[(kq * 4 + 0) * 68 + r] = v.x;
            xsT[(kq * 4 + 1) * 68 + r] = v.y;
            xsT[(kq * 4 + 2) * 68 + r] = v.z;
            xsT[(kq * 4 + 3) * 68 + r] = v.w;
        }
        // stage W tile (32 k x 64 c), linear copy
        #pragma unroll
        for (int q0 = 0; q0 < 2; ++q0) {
            int q = t + q0 * 256;          // float4 index over 512
            int k = q >> 4, c4 = (q & 15) * 4;
            *(float4*)&ws[k * 64 + c4] = *(const float4*)&W[(size_t)(kt + k) * 64 + c4];
        }
        __syncthreads();

        #pragma unroll
        for (int k = 0; k < 32; ++k) {
            float4 a = *(const float4*)&xsT[k * 68 + ty * 4];
            float4 b = *(const float4*)&ws[k * 64 + tx * 4];
            float av[4] = {a.x, a.y, a.z, a.w};
            float bv[4] = {b.x, b.y, b.z, b.w};
            #pragma unroll
            for (int i = 0; i < 4; ++i)
                #pragma unroll
                for (int j = 0; j < 4; ++j)
                    acc[i][j] = fmaf(av[i], bv[j], acc[i][j]);
        }
        __syncthreads();
    }

    #pragma unroll
    for (int i = 0; i < 4; ++i) {
        int row = row0 + ty * 4 + i;
        if (row < N) {
            float dv = dinv[row];
            float4 o = { dv * acc[i][0], dv * acc[i][1], dv * acc[i][2], dv * acc[i][3] };
            *(float4*)&h1s[(size_t)row * HID + tx * 4] = o;
        }
    }
}

// ---------------- agg1: a1[i] = relu(dinv[i]*(h1s[i] + sum_e h1s[src]) + b1) ----------------
__global__ __launch_bounds__(256) void k_agg1(const float* __restrict__ h1s,
                                              const int* __restrict__ rowptr,
                                              const int* __restrict__ ssort,
                                              const float* __restrict__ dinv,
                                              const float* __restrict__ b1,
                                              float* __restrict__ a1, int N) {
    int lane = threadIdx.x & 63;
    int node = blockIdx.x * 4 + (threadIdx.x >> 6);
    if (node >= N) return;
    float s = h1s[(size_t)node * HID + lane];   // self-loop term
    int e = rowptr[node], end = rowptr[node + 1];
    for (; e + 1 < end; e += 2) {
        int s0 = ssort[e], s1 = ssort[e + 1];
        s += h1s[(size_t)s0 * HID + lane];
        s += h1s[(size_t)s1 * HID + lane];
    }
    if (e < end) s += h1s[(size_t)ssort[e] * HID + lane];
    float v = dinv[node] * s + b1[lane];
    a1[(size_t)node * HID + lane] = fmaxf(v, 0.0f);
}

// ---------------- GEMM2: h2s[i][c] = dinv[i] * dot(a1[i,:64], W2[:,c]), c<40 ----------------
__global__ __launch_bounds__(256) void k_gemm2(const float* __restrict__ a1,
                                               const float* __restrict__ W2,
                                               const float* __restrict__ dinv,
                                               float* __restrict__ h2s, int N) {
    __shared__ float as[32 * 68];         // [r][k], stride 68
    __shared__ float wl[HID * OUTC];      // 2560 floats
    int t = threadIdx.x;
    int row0 = blockIdx.x * 32;

    #pragma unroll
    for (int q0 = 0; q0 < 2; ++q0) {
        int q = t + q0 * 256;             // float4 index over 512
        int r = q >> 4, kq = q & 15;
        int row = row0 + r; if (row >= N) row = N - 1;
        float4 v = *(const float4*)&a1[(size_t)row * HID + kq * 4];
        *(float4*)&as[r * 68 + kq * 4] = v;
    }
    #pragma unroll
    for (int q0 = 0; q0 < 3; ++q0) {
        int q = t + q0 * 256;             // float4 index over 640
        if (q < 640) *(float4*)&wl[q * 4] = *(const float4*)&W2[q * 4];
    }
    __syncthreads();

    int lr = t >> 3, lc0 = t & 7;
    int row = row0 + lr;
    float acc[5] = {};
    #pragma unroll
    for (int k = 0; k < HID; ++k) {
        float a = as[lr * 68 + k];
        #pragma unroll
        for (int m = 0; m < 5; ++m)
            acc[m] = fmaf(a, wl[k * OUTC + lc0 + m * 8], acc[m]);
    }
    if (row < N) {
        float dv = dinv[row];
        #pragma unroll
        for (int m = 0; m < 5; ++m)
            h2s[(size_t)row * OUTC + lc0 + m * 8] = dv * acc[m];
    }
}

// ---------------- agg2 + bias + softmax ----------------
__global__ __launch_bounds__(256) void k_agg2(const float* __restrict__ h2s,
                                              const int* __restrict__ rowptr,
                                              const int* __restrict__ ssort,
                                              const float* __restrict__ dinv,
                                              const float* __restrict__ b2,
                                              float* __restrict__ out, int N) {
    int lane = threadIdx.x & 63;
    int node = blockIdx.x * 4 + (threadIdx.x >> 6);
    if (node >= N) return;
    bool act = lane < OUTC;
    float s = act ? h2s[(size_t)node * OUTC + lane] : 0.0f;
    int e = rowptr[node], end = rowptr[node + 1];
    for (; e < end; ++e) {
        int sr = ssort[e];
        if (act) s += h2s[(size_t)sr * OUTC + lane];
    }
    float v = act ? (dinv[node] * s + b2[lane]) : -INFINITY;
    float m = v;
    #pragma unroll
    for (int o = 32; o; o >>= 1) m = fmaxf(m, __shfl_xor(m, o));
    float p = act ? expf(v - m) : 0.0f;
    float su = p;
    #pragma unroll
    for (int o = 32; o; o >>= 1) su += __shfl_xor(su, o);
    if (act) out[(size_t)node * OUTC + lane] = p / su;
}

static inline size_t alignup(size_t v) { return (v + 255) & ~(size_t)255; }

extern "C" void kernel_launch(void* const* d_in, const int* in_sizes, int n_in,
                              void* d_out, int out_size, void* d_ws, size_t ws_size,
                              hipStream_t stream) {
    const float* x  = (const float*)d_in[0];
    const int*   ei = (const int*)d_in[1];
    const float* W1 = (const float*)d_in[2];
    const float* b1 = (const float*)d_in[3];
    const float* W2 = (const float*)d_in[4];
    const float* b2 = (const float*)d_in[5];

    const int N = in_sizes[0] / IN_C;
    const int E = in_sizes[1] / 2;
    const int* src = ei;
    const int* dst = ei + E;

    char* w = (char*)d_ws;
    int* cnt    = (int*)w;   w += alignup((size_t)N * 4);
    int* rowptr = (int*)w;   w += alignup((size_t)(N + 1) * 4);
    int* bsum   = (int*)w;   w += alignup(256 * 4);
    int* bpre   = (int*)w;   w += alignup(256 * 4);
    int* fillc  = (int*)w;   w += alignup((size_t)N * 4);
    int* ssort  = (int*)w;   w += alignup((size_t)E * 4);
    float* dinv = (float*)w; w += alignup((size_t)N * 4);
    float* h1s  = (float*)w; w += alignup((size_t)N * HID * 4);
    float* a1   = (float*)w; w += alignup((size_t)N * HID * 4);
    float* h2s  = (float*)w; w += alignup((size_t)N * OUTC * 4);

    hipMemsetAsync(cnt,   0, (size_t)N * 4, stream);
    hipMemsetAsync(fillc, 0, (size_t)N * 4, stream);

    const int nb = (N + 255) / 256;
    k_hist <<<(E + 255) / 256, 256, 0, stream>>>(dst, E, cnt);
    k_scan1<<<nb, 256, 0, stream>>>(cnt, N, rowptr, bsum);
    k_scan2<<<1, 256, 0, stream>>>(bsum, nb, bpre);
    k_scan3<<<nb, 256, 0, stream>>>(rowptr, bpre, cnt, dinv, N, E);
    k_fill <<<(E + 255) / 256, 256, 0, stream>>>(src, dst, E, rowptr, fillc, ssort);

    k_gemm1<<<(N + 63) / 64, 256, 0, stream>>>(x, W1, dinv, h1s, N);
    k_agg1 <<<(N + 3) / 4, 256, 0, stream>>>(h1s, rowptr, ssort, dinv, b1, a1, N);
    k_gemm2<<<(N + 31) / 32, 256, 0, stream>>>(a1, W2, dinv, h2s, N);
    k_agg2 <<<(N + 3) / 4, 256, 0, stream>>>(h2s, rowptr, ssort, dinv, b2, (float*)d_out, N);
}

// Round 2
// 235.860 us; speedup vs baseline: 1.2455x; 1.2455x over previous
//
#include <hip/hip_runtime.h>
#include <math.h>

#define IN_C 512
#define HID  64
#define OUTC 40

// ---------------- histogram of dst ----------------
__global__ void k_hist(const int* __restrict__ dst, int E, int* __restrict__ cnt) {
    int i = blockIdx.x * blockDim.x + threadIdx.x;
    if (i < E) atomicAdd(&cnt[dst[i]], 1);
}

// ---------------- prefix scan (3 kernels) ----------------
__global__ void k_scan1(const int* __restrict__ cnt, int N,
                        int* __restrict__ rowptr, int* __restrict__ bsum) {
    __shared__ int s[256];
    int t = threadIdx.x;
    int i = blockIdx.x * 256 + t;
    int v = (i < N) ? cnt[i] : 0;
    int x = v;
    s[t] = x; __syncthreads();
    #pragma unroll
    for (int o = 1; o < 256; o <<= 1) {
        int y = (t >= o) ? s[t - o] : 0;
        __syncthreads();
        x += y; s[t] = x;
        __syncthreads();
    }
    if (i < N) rowptr[i] = x - v;          // exclusive
    if (t == 255) bsum[blockIdx.x] = x;    // block total
}

__global__ void k_scan2(const int* __restrict__ bsum, int nb, int* __restrict__ bpre) {
    __shared__ int s[256];
    int t = threadIdx.x;
    int v = (t < nb) ? bsum[t] : 0;
    int x = v;
    s[t] = x; __syncthreads();
    #pragma unroll
    for (int o = 1; o < 256; o <<= 1) {
        int y = (t >= o) ? s[t - o] : 0;
        __syncthreads();
        x += y; s[t] = x;
        __syncthreads();
    }
    bpre[t] = x - v;
}

__global__ void k_scan3(int* __restrict__ rowptr, const int* __restrict__ bpre,
                        const int* __restrict__ cnt, float* __restrict__ dinv,
                        int N, int E) {
    int i = blockIdx.x * blockDim.x + threadIdx.x;
    if (i < N) {
        rowptr[i] += bpre[i >> 8];
        dinv[i] = rsqrtf(1.0f + (float)cnt[i]);   // self-loop => deg >= 1
        if (i == 0) rowptr[N] = E;
    }
}

// ---------------- counting-sort fill ----------------
__global__ void k_fill(const int* __restrict__ src, const int* __restrict__ dst, int E,
                       const int* __restrict__ rowptr, int* __restrict__ fillc,
                       int* __restrict__ ssort) {
    int i = blockIdx.x * blockDim.x + threadIdx.x;
    if (i < E) {
        int d = dst[i];
        int p = rowptr[d] + atomicAdd(&fillc[d], 1);
        ssort[p] = src[i];
    }
}

// ---------------- GEMM1: h1s[i][c] = dinv[i] * dot(x[i,:512], W1[:,c]), c<64 ----------------
__global__ __launch_bounds__(256) void k_gemm1(const float* __restrict__ x,
                                               const float* __restrict__ W,
                                               const float* __restrict__ dinv,
                                               float* __restrict__ h1s, int N) {
    __shared__ float xsT[32 * 68];   // [k][r], stride 68 (16B-aligned rows, bank-spread)
    __shared__ float ws[32 * 64];    // [k][c]
    int t = threadIdx.x;
    int row0 = blockIdx.x * 64;
    int tx = t & 15, ty = t >> 4;

    float acc[4][4] = {};

    for (int kt = 0; kt < IN_C; kt += 32) {
        // stage x tile (64 rows x 32 k), transposed into xsT
        #pragma unroll
        for (int q0 = 0; q0 < 2; ++q0) {
            int q = t + q0 * 256;          // float4 index over 512
            int r = q >> 3, kq = q & 7;
            int row = row0 + r; if (row >= N) row = N - 1;
            const float4 v = *(const float4*)&x[(size_t)row * IN_C + kt + kq * 4];
            xsT[(kq * 4 + 0) * 68 + r] = v.x;
            xsT[(kq * 4 + 1) * 68 + r] = v.y;
            xsT[(kq * 4 + 2) * 68 + r] = v.z;
            xsT[(kq * 4 + 3) * 68 + r] = v.w;
        }
        // stage W tile (32 k x 64 c), linear copy
        #pragma unroll
        for (int q0 = 0; q0 < 2; ++q0) {
            int q = t + q0 * 256;          // float4 index over 512
            int k = q >> 4, c4 = (q & 15) * 4;
            *(float4*)&ws[k * 64 + c4] = *(const float4*)&W[(size_t)(kt + k) * 64 + c4];
        }
        __syncthreads();

        #pragma unroll
        for (int k = 0; k < 32; ++k) {
            float4 a = *(const float4*)&xsT[k * 68 + ty * 4];
            float4 b = *(const float4*)&ws[k * 64 + tx * 4];
            float av[4] = {a.x, a.y, a.z, a.w};
            float bv[4] = {b.x, b.y, b.z, b.w};
            #pragma unroll
            for (int i = 0; i < 4; ++i)
                #pragma unroll
                for (int j = 0; j < 4; ++j)
                    acc[i][j] = fmaf(av[i], bv[j], acc[i][j]);
        }
        __syncthreads();
    }

    #pragma unroll
    for (int i = 0; i < 4; ++i) {
        int row = row0 + ty * 4 + i;
        if (row < N) {
            float dv = dinv[row];
            float4 o = { dv * acc[i][0], dv * acc[i][1], dv * acc[i][2], dv * acc[i][3] };
            *(float4*)&h1s[(size_t)row * HID + tx * 4] = o;
        }
    }
}

// ---------------- agg1: a1[i] = relu(dinv[i]*(h1s[i] + sum_e h1s[src]) + b1) ----------------
// 8-way unrolled edge loop: 8 independent gathers in flight per wave (MLP fix).
__global__ __launch_bounds__(256) void k_agg1(const float* __restrict__ h1s,
                                              const int* __restrict__ rowptr,
                                              const int* __restrict__ ssort,
                                              const float* __restrict__ dinv,
                                              const float* __restrict__ b1,
                                              float* __restrict__ a1, int N) {
    int lane = threadIdx.x & 63;
    int node = blockIdx.x * 4 + (threadIdx.x >> 6);
    if (node >= N) return;
    float s0 = h1s[(size_t)node * HID + lane];   // self-loop term
    float s1 = 0.f, s2 = 0.f, s3 = 0.f, s4 = 0.f, s5 = 0.f, s6 = 0.f, s7 = 0.f;
    int e0 = rowptr[node], end = rowptr[node + 1];
    for (int e = e0; e < end; e += 8) {
        int ix[8];
        #pragma unroll
        for (int k = 0; k < 8; ++k) ix[k] = (e + k < end) ? ssort[e + k] : ssort[e];
        float v[8];
        #pragma unroll
        for (int k = 0; k < 8; ++k) v[k] = h1s[(size_t)ix[k] * HID + lane];
        s0 += v[0];
        s1 += (e + 1 < end) ? v[1] : 0.f;
        s2 += (e + 2 < end) ? v[2] : 0.f;
        s3 += (e + 3 < end) ? v[3] : 0.f;
        s4 += (e + 4 < end) ? v[4] : 0.f;
        s5 += (e + 5 < end) ? v[5] : 0.f;
        s6 += (e + 6 < end) ? v[6] : 0.f;
        s7 += (e + 7 < end) ? v[7] : 0.f;
    }
    float s = ((s0 + s1) + (s2 + s3)) + ((s4 + s5) + (s6 + s7));
    float v = dinv[node] * s + b1[lane];
    a1[(size_t)node * HID + lane] = fmaxf(v, 0.0f);
}

// ---------------- GEMM2: h2s[i][c] = dinv[i] * dot(a1[i,:64], W2[:,c]), c<40 ----------------
__global__ __launch_bounds__(256) void k_gemm2(const float* __restrict__ a1,
                                               const float* __restrict__ W2,
                                               const float* __restrict__ dinv,
                                               float* __restrict__ h2s, int N) {
    __shared__ float as[32 * 68];         // [r][k], stride 68
    __shared__ float wl[HID * OUTC];      // 2560 floats
    int t = threadIdx.x;
    int row0 = blockIdx.x * 32;

    #pragma unroll
    for (int q0 = 0; q0 < 2; ++q0) {
        int q = t + q0 * 256;             // float4 index over 512
        int r = q >> 4, kq = q & 15;
        int row = row0 + r; if (row >= N) row = N - 1;
        float4 v = *(const float4*)&a1[(size_t)row * HID + kq * 4];
        *(float4*)&as[r * 68 + kq * 4] = v;
    }
    #pragma unroll
    for (int q0 = 0; q0 < 3; ++q0) {
        int q = t + q0 * 256;             // float4 index over 640
        if (q < 640) *(float4*)&wl[q * 4] = *(const float4*)&W2[q * 4];
    }
    __syncthreads();

    int lr = t >> 3, lc0 = t & 7;
    int row = row0 + lr;
    float acc[5] = {};
    #pragma unroll
    for (int k = 0; k < HID; ++k) {
        float a = as[lr * 68 + k];
        #pragma unroll
        for (int m = 0; m < 5; ++m)
            acc[m] = fmaf(a, wl[k * OUTC + lc0 + m * 8], acc[m]);
    }
    if (row < N) {
        float dv = dinv[row];
        #pragma unroll
        for (int m = 0; m < 5; ++m)
            h2s[(size_t)row * OUTC + lc0 + m * 8] = dv * acc[m];
    }
}

// ---------------- agg2 + bias + softmax (8-way unrolled gathers) ----------------
__global__ __launch_bounds__(256) void k_agg2(const float* __restrict__ h2s,
                                              const int* __restrict__ rowptr,
                                              const int* __restrict__ ssort,
                                              const float* __restrict__ dinv,
                                              const float* __restrict__ b2,
                                              float* __restrict__ out, int N) {
    int lane = threadIdx.x & 63;
    int node = blockIdx.x * 4 + (threadIdx.x >> 6);
    if (node >= N) return;
    bool act = lane < OUTC;
    float s0 = act ? h2s[(size_t)node * OUTC + lane] : 0.0f;
    float s1 = 0.f, s2 = 0.f, s3 = 0.f, s4 = 0.f, s5 = 0.f, s6 = 0.f, s7 = 0.f;
    int e0 = rowptr[node], end = rowptr[node + 1];
    for (int e = e0; e < end; e += 8) {
        int ix[8];
        #pragma unroll
        for (int k = 0; k < 8; ++k) ix[k] = (e + k < end) ? ssort[e + k] : ssort[e];
        float v[8];
        #pragma unroll
        for (int k = 0; k < 8; ++k) v[k] = act ? h2s[(size_t)ix[k] * OUTC + lane] : 0.f;
        s0 += v[0];
        s1 += (e + 1 < end) ? v[1] : 0.f;
        s2 += (e + 2 < end) ? v[2] : 0.f;
        s3 += (e + 3 < end) ? v[3] : 0.f;
        s4 += (e + 4 < end) ? v[4] : 0.f;
        s5 += (e + 5 < end) ? v[5] : 0.f;
        s6 += (e + 6 < end) ? v[6] : 0.f;
        s7 += (e + 7 < end) ? v[7] : 0.f;
    }
    float s = ((s0 + s1) + (s2 + s3)) + ((s4 + s5) + (s6 + s7));
    float v = act ? (dinv[node] * s + b2[lane]) : -INFINITY;
    float m = v;
    #pragma unroll
    for (int o = 32; o; o >>= 1) m = fmaxf(m, __shfl_xor(m, o));
    float p = act ? expf(v - m) : 0.0f;
    float su = p;
    #pragma unroll
    for (int o = 32; o; o >>= 1) su += __shfl_xor(su, o);
    if (act) out[(size_t)node * OUTC + lane] = p / su;
}

static inline size_t alignup(size_t v) { return (v + 255) & ~(size_t)255; }

extern "C" void kernel_launch(void* const* d_in, const int* in_sizes, int n_in,
                              void* d_out, int out_size, void* d_ws, size_t ws_size,
                              hipStream_t stream) {
    const float* x  = (const float*)d_in[0];
    const int*   ei = (const int*)d_in[1];
    const float* W1 = (const float*)d_in[2];
    const float* b1 = (const float*)d_in[3];
    const float* W2 = (const float*)d_in[4];
    const float* b2 = (const float*)d_in[5];

    const int N = in_sizes[0] / IN_C;
    const int E = in_sizes[1] / 2;
    const int* src = ei;
    const int* dst = ei + E;

    char* w = (char*)d_ws;
    int* cnt    = (int*)w;   w += alignup((size_t)N * 4);
    int* rowptr = (int*)w;   w += alignup((size_t)(N + 1) * 4);
    int* bsum   = (int*)w;   w += alignup(256 * 4);
    int* bpre   = (int*)w;   w += alignup(256 * 4);
    int* fillc  = (int*)w;   w += alignup((size_t)N * 4);
    int* ssort  = (int*)w;   w += alignup((size_t)E * 4);
    float* dinv = (float*)w; w += alignup((size_t)N * 4);
    float* h1s  = (float*)w; w += alignup((size_t)N * HID * 4);
    float* a1   = (float*)w; w += alignup((size_t)N * HID * 4);
    float* h2s  = (float*)w; w += alignup((size_t)N * OUTC * 4);

    hipMemsetAsync(cnt,   0, (size_t)N * 4, stream);
    hipMemsetAsync(fillc, 0, (size_t)N * 4, stream);

    const int nb = (N + 255) / 256;
    k_hist <<<(E + 255) / 256, 256, 0, stream>>>(dst, E, cnt);
    k_scan1<<<nb, 256, 0, stream>>>(cnt, N, rowptr, bsum);
    k_scan2<<<1, 256, 0, stream>>>(bsum, nb, bpre);
    k_scan3<<<nb, 256, 0, stream>>>(rowptr, bpre, cnt, dinv, N, E);
    k_fill <<<(E + 255) / 256, 256, 0, stream>>>(src, dst, E, rowptr, fillc, ssort);

    k_gemm1<<<(N + 63) / 64, 256, 0, stream>>>(x, W1, dinv, h1s, N);
    k_agg1 <<<(N + 3) / 4, 256, 0, stream>>>(h1s, rowptr, ssort, dinv, b1, a1, N);
    k_gemm2<<<(N + 31) / 32, 256, 0, stream>>>(a1, W2, dinv, h2s, N);
    k_agg2 <<<(N + 3) / 4, 256, 0, stream>>>(h2s, rowptr, ssort, dinv, b2, (float*)d_out, N);
}